// Round 1
// baseline (845.158 us; speedup 1.0000x reference)
//
#include <hip/hip_runtime.h>

#define NN 100000
#define NE 1600000

__device__ __forceinline__ float wave_red(float v) {
#pragma unroll
    for (int off = 32; off > 0; off >>= 1) v += __shfl_down(v, off, 64);
    return v;
}

// ---------------- edge block: MLP(19->16->2) + scatter-add + mean partials ----
template <bool NEED_SUM>
__global__ __launch_bounds__(256) void edge_kernel(
    const int* __restrict__ ei, const float* __restrict__ x,
    const float* __restrict__ eattr, const float* __restrict__ gptr,
    const float* __restrict__ W1, const float* __restrict__ B1,
    const float* __restrict__ W2, const float* __restrict__ B2,
    float* __restrict__ eout, float* __restrict__ agg, float* __restrict__ esum)
{
    __shared__ float sW1[19 * 16];
    __shared__ float sW2[16 * 2];
    __shared__ float sb1[16];
    __shared__ float sb2[2];
    for (int i = threadIdx.x; i < 304; i += 256) sW1[i] = W1[i];
    if (threadIdx.x < 32) sW2[threadIdx.x] = W2[threadIdx.x];
    if (threadIdx.x < 16) sb1[threadIdx.x] = B1[threadIdx.x];
    if (threadIdx.x < 2)  sb2[threadIdx.x] = B2[threadIdx.x];
    __syncthreads();

    int e = blockIdx.x * 256 + threadIdx.x;
    float o0 = 0.f, o1 = 0.f;
    if (e < NE) {
        int row = ei[e];
        int col = ei[NE + e];
        float in[19];
        in[0] = gptr[0];
        const float4* xr = reinterpret_cast<const float4*>(x + (size_t)row * 8);
        float4 a0 = xr[0], a1 = xr[1];
        in[1] = a0.x; in[2] = a0.y; in[3] = a0.z; in[4] = a0.w;
        in[5] = a1.x; in[6] = a1.y; in[7] = a1.z; in[8] = a1.w;
        const float4* xc = reinterpret_cast<const float4*>(x + (size_t)col * 8);
        float4 c0 = xc[0], c1 = xc[1];
        in[9] = c0.x; in[10] = c0.y; in[11] = c0.z; in[12] = c0.w;
        in[13] = c1.x; in[14] = c1.y; in[15] = c1.z; in[16] = c1.w;
        float2 ea = reinterpret_cast<const float2*>(eattr)[e];
        in[17] = ea.x; in[18] = ea.y;

        float h[16];
#pragma unroll
        for (int j = 0; j < 16; j++) h[j] = sb1[j];
#pragma unroll
        for (int k = 0; k < 19; k++) {
            float v = in[k];
            const float4* wr = reinterpret_cast<const float4*>(sW1 + k * 16);
            float4 w0 = wr[0], w1 = wr[1], w2 = wr[2], w3 = wr[3];
            h[0]  += v * w0.x; h[1]  += v * w0.y; h[2]  += v * w0.z; h[3]  += v * w0.w;
            h[4]  += v * w1.x; h[5]  += v * w1.y; h[6]  += v * w1.z; h[7]  += v * w1.w;
            h[8]  += v * w2.x; h[9]  += v * w2.y; h[10] += v * w2.z; h[11] += v * w2.w;
            h[12] += v * w3.x; h[13] += v * w3.y; h[14] += v * w3.z; h[15] += v * w3.w;
        }
        o0 = sb2[0]; o1 = sb2[1];
#pragma unroll
        for (int j = 0; j < 16; j++) {
            float hj = fmaxf(h[j], 0.f);
            o0 += hj * sW2[2 * j];
            o1 += hj * sW2[2 * j + 1];
        }
        reinterpret_cast<float2*>(eout)[e] = make_float2(o0, o1);
        atomicAdd(&agg[(size_t)row * 2], o0);
        atomicAdd(&agg[(size_t)row * 2 + 1], o1);
    }
    if (NEED_SUM) {
        float r0 = wave_red(o0);
        float r1 = wave_red(o1);
        __shared__ float red[4][2];
        int wave = threadIdx.x >> 6, lane = threadIdx.x & 63;
        if (lane == 0) { red[wave][0] = r0; red[wave][1] = r1; }
        __syncthreads();
        if (threadIdx.x == 0) {
            float s0 = red[0][0] + red[1][0] + red[2][0] + red[3][0];
            float s1 = red[0][1] + red[1][1] + red[2][1] + red[3][1];
            atomicAdd(&esum[0], s0);
            atomicAdd(&esum[1], s1);
        }
    }
}

// ---------------- node block: MLP(11->16->8) + mean partials -----------------
template <bool NEED_SUM>
__global__ __launch_bounds__(256) void node_kernel(
    const float* __restrict__ x, const float* __restrict__ agg,
    const float* __restrict__ gptr,
    const float* __restrict__ W1, const float* __restrict__ B1,
    const float* __restrict__ W2, const float* __restrict__ B2,
    float* __restrict__ xout, float* __restrict__ nsum)
{
    __shared__ float sW1[11 * 16];
    __shared__ float sW2[16 * 8];
    __shared__ float sb1[16];
    __shared__ float sb2[8];
    if (threadIdx.x < 176) sW1[threadIdx.x] = W1[threadIdx.x];
    if (threadIdx.x < 128) sW2[threadIdx.x] = W2[threadIdx.x];
    if (threadIdx.x < 16) sb1[threadIdx.x] = B1[threadIdx.x];
    if (threadIdx.x < 8)  sb2[threadIdx.x] = B2[threadIdx.x];
    __syncthreads();

    int i = blockIdx.x * 256 + threadIdx.x;
    float out[8];
#pragma unroll
    for (int m = 0; m < 8; m++) out[m] = 0.f;

    if (i < NN) {
        float in[11];
        in[0] = gptr[0];
        const float4* xi = reinterpret_cast<const float4*>(x + (size_t)i * 8);
        float4 a0 = xi[0], a1 = xi[1];
        in[1] = a0.x; in[2] = a0.y; in[3] = a0.z; in[4] = a0.w;
        in[5] = a1.x; in[6] = a1.y; in[7] = a1.z; in[8] = a1.w;
        float2 ag = reinterpret_cast<const float2*>(agg)[i];
        in[9] = ag.x; in[10] = ag.y;

        float h[16];
#pragma unroll
        for (int j = 0; j < 16; j++) h[j] = sb1[j];
#pragma unroll
        for (int k = 0; k < 11; k++) {
            float v = in[k];
            const float4* wr = reinterpret_cast<const float4*>(sW1 + k * 16);
            float4 w0 = wr[0], w1 = wr[1], w2 = wr[2], w3 = wr[3];
            h[0]  += v * w0.x; h[1]  += v * w0.y; h[2]  += v * w0.z; h[3]  += v * w0.w;
            h[4]  += v * w1.x; h[5]  += v * w1.y; h[6]  += v * w1.z; h[7]  += v * w1.w;
            h[8]  += v * w2.x; h[9]  += v * w2.y; h[10] += v * w2.z; h[11] += v * w2.w;
            h[12] += v * w3.x; h[13] += v * w3.y; h[14] += v * w3.z; h[15] += v * w3.w;
        }
#pragma unroll
        for (int m = 0; m < 8; m++) out[m] = sb2[m];
#pragma unroll
        for (int j = 0; j < 16; j++) {
            float hj = fmaxf(h[j], 0.f);
#pragma unroll
            for (int m = 0; m < 8; m++) out[m] += hj * sW2[j * 8 + m];
        }
        float4* xo = reinterpret_cast<float4*>(xout + (size_t)i * 8);
        xo[0] = make_float4(out[0], out[1], out[2], out[3]);
        xo[1] = make_float4(out[4], out[5], out[6], out[7]);
    }
    if (NEED_SUM) {
        float r[8];
#pragma unroll
        for (int m = 0; m < 8; m++) r[m] = wave_red(out[m]);
        __shared__ float red[4][8];
        int wave = threadIdx.x >> 6, lane = threadIdx.x & 63;
        if (lane == 0) {
#pragma unroll
            for (int m = 0; m < 8; m++) red[wave][m] = r[m];
        }
        __syncthreads();
        if (threadIdx.x == 0) {
#pragma unroll
            for (int m = 0; m < 8; m++) {
                float s = red[0][m] + red[1][m] + red[2][m] + red[3][m];
                atomicAdd(&nsum[m], s);
            }
        }
    }
}

// ---------------- global block: MLP(11->16->1), single thread ----------------
__global__ void glob_kernel(const float* __restrict__ esum, const float* __restrict__ nsum,
                            const float* __restrict__ gold,
                            const float* __restrict__ W1, const float* __restrict__ B1,
                            const float* __restrict__ W2, const float* __restrict__ B2,
                            float* __restrict__ gnew)
{
    if (threadIdx.x == 0 && blockIdx.x == 0) {
        float in[11];
#pragma unroll
        for (int j = 0; j < 8; j++) in[j] = nsum[j] * (1.0f / NN);
        in[8] = esum[0] * (1.0f / NE);
        in[9] = esum[1] * (1.0f / NE);
        in[10] = gold[0];
        float acc = B2[0];
#pragma unroll
        for (int j = 0; j < 16; j++) {
            float h = B1[j];
#pragma unroll
            for (int k = 0; k < 11; k++) h += in[k] * W1[k * 16 + j];
            acc += fmaxf(h, 0.f) * W2[j];
        }
        gnew[0] = acc;
    }
}

extern "C" void kernel_launch(void* const* d_in, const int* in_sizes, int n_in,
                              void* d_out, int out_size, void* d_ws, size_t ws_size,
                              hipStream_t stream) {
    const float* x     = (const float*)d_in[0];
    const int*   ei    = (const int*)d_in[1];
    const float* eattr = (const float*)d_in[2];
    const float* g     = (const float*)d_in[3];
    const float* eW1 = (const float*)d_in[4];
    const float* eB1 = (const float*)d_in[5];
    const float* eW2 = (const float*)d_in[6];
    const float* eB2 = (const float*)d_in[7];
    const float* nW1 = (const float*)d_in[8];
    const float* nB1 = (const float*)d_in[9];
    const float* nW2 = (const float*)d_in[10];
    const float* nB2 = (const float*)d_in[11];
    const float* gW1 = (const float*)d_in[12];
    const float* gB1 = (const float*)d_in[13];
    const float* gW2 = (const float*)d_in[14];
    const float* gB2 = (const float*)d_in[15];
    float* out = (float*)d_out;

    char* ws = (char*)d_ws;
    float* xb0 = (float*)(ws);                 // 100000*8 floats = 3.2e6 B
    float* xb1 = (float*)(ws + 3200000);       // 3.2e6 B
    float* eb0 = (float*)(ws + 6400000);       // 1.6M*2 floats = 12.8e6 B
    float* eb1 = (float*)(ws + 19200000);      // 12.8e6 B
    float* agg = (float*)(ws + 32000000);      // 100000*2 floats = 800000 B
    float* esum = (float*)(ws + 32800000);     // 2 floats
    float* nsum = esum + 2;                    // 8 floats
    float* g1 = (float*)(ws + 32800064);
    float* g2 = g1 + 1;

    dim3 blk(256);
    dim3 egrid((NE + 255) / 256);
    dim3 ngrid((NN + 255) / 256);

    // ---- layer 0 ----
    hipMemsetAsync(agg, 0, 800000 + 48, stream);
    edge_kernel<true><<<egrid, blk, 0, stream>>>(ei, x, eattr, g,
        eW1, eB1, eW2, eB2, eb0, agg, esum);
    node_kernel<true><<<ngrid, blk, 0, stream>>>(x, agg, g,
        nW1, nB1, nW2, nB2, xb0, nsum);
    glob_kernel<<<1, 64, 0, stream>>>(esum, nsum, g, gW1, gB1, gW2, gB2, g1);

    // ---- layer 1 ----
    hipMemsetAsync(agg, 0, 800000 + 48, stream);
    edge_kernel<true><<<egrid, blk, 0, stream>>>(ei, xb0, eb0, g1,
        eW1 + 304, eB1 + 16, eW2 + 32, eB2 + 2, eb1, agg, esum);
    node_kernel<true><<<ngrid, blk, 0, stream>>>(xb0, agg, g1,
        nW1 + 176, nB1 + 16, nW2 + 128, nB2 + 8, xb1, nsum);
    glob_kernel<<<1, 64, 0, stream>>>(esum, nsum, g1, gW1 + 176, gB1 + 16, gW2 + 16, gB2 + 1, g2);

    // ---- layer 2 (no global block needed; node output -> d_out) ----
    hipMemsetAsync(agg, 0, 800000 + 48, stream);
    edge_kernel<false><<<egrid, blk, 0, stream>>>(ei, xb1, eb1, g2,
        eW1 + 608, eB1 + 32, eW2 + 64, eB2 + 4, eb0, agg, esum);
    node_kernel<false><<<ngrid, blk, 0, stream>>>(xb1, agg, g2,
        nW1 + 352, nB1 + 32, nW2 + 256, nB2 + 16, out, nsum);
}